// Round 2
// baseline (341.184 us; speedup 1.0000x reference)
//
#include <hip/hip_runtime.h>
#include <math.h>

// Problem constants (B,T,C,H) = (4, 2048, 1024, 16), D = 64.
#define B_   4
#define T_   2048
#define C_   1024
#define H_   16
#define D_   64
#define TC3  3072   // 3*C

typedef __attribute__((ext_vector_type(8))) short short8;
typedef __attribute__((ext_vector_type(4))) short short4b;
typedef __attribute__((ext_vector_type(8))) unsigned short ushortv8;
typedef __attribute__((ext_vector_type(4))) float f32x4;

__device__ __forceinline__ float bf2f(unsigned short u) {
  unsigned int x = ((unsigned int)u) << 16;
  float f; __builtin_memcpy(&f, &x, 4); return f;
}
__device__ __forceinline__ unsigned short f2bf(float f) {   // round-nearest-even
  unsigned int x; __builtin_memcpy(&x, &f, 4);
  x += 0x7fff + ((x >> 16) & 1);
  return (unsigned short)(x >> 16);
}

#define MFMA32(a, b, c) __builtin_amdgcn_mfma_f32_16x16x32_bf16(a, b, c, 0, 0, 0)
#if __has_builtin(__builtin_amdgcn_mfma_f32_16x16x16_bf16)
#define MFMA16(a, b, c) __builtin_amdgcn_mfma_f32_16x16x16_bf16(a, b, c, 0, 0, 0)
#else
#define MFMA16(a, b, c) __builtin_amdgcn_mfma_f32_16x16x16bf16_1k(a, b, c, 0, 0, 0)
#endif

#define GLOAD_LDS(gp, lp) __builtin_amdgcn_global_load_lds( \
    (const __attribute__((address_space(1))) unsigned int*)(gp), \
    (__attribute__((address_space(3))) unsigned int*)(lp), 16, 0, 0)

// ---------------------------------------------------------------------------
// x f32 -> bf16 (lets GEMM1 use the pure-bf16 global_load_lds staging path).
// ---------------------------------------------------------------------------
__global__ __launch_bounds__(256)
void convert_bf16(const float* __restrict__ x, unsigned short* __restrict__ xb) {
  const size_t i = ((size_t)blockIdx.x * 256 + threadIdx.x) * 8;
  float4 f0 = *(const float4*)(x + i);
  float4 f1 = *(const float4*)(x + i + 4);
  ushortv8 u = { f2bf(f0.x), f2bf(f0.y), f2bf(f0.z), f2bf(f0.w),
                 f2bf(f1.x), f2bf(f1.y), f2bf(f1.z), f2bf(f1.w) };
  *(ushortv8*)(xb + i) = u;
}

// ---------------------------------------------------------------------------
// Transpose + fp32->bf16 convert: W[K][N] f32 -> WT[N][K] bf16. 64x64 tiles.
// ---------------------------------------------------------------------------
__global__ __launch_bounds__(256)
void transpose_bf16(const float* __restrict__ W, unsigned short* __restrict__ WT,
                    int K, int N) {
  __shared__ float tile[64][65];
  const int k0 = blockIdx.y * 64, n0 = blockIdx.x * 64;
  const int r = threadIdx.x >> 4, c4 = (threadIdx.x & 15) * 4;
#pragma unroll
  for (int p = 0; p < 4; ++p) {
    int kk = p * 16 + r;
    float4 v = *(const float4*)(W + (size_t)(k0 + kk) * N + n0 + c4);
    tile[kk][c4 + 0] = v.x; tile[kk][c4 + 1] = v.y;
    tile[kk][c4 + 2] = v.z; tile[kk][c4 + 3] = v.w;
  }
  __syncthreads();
#pragma unroll
  for (int p = 0; p < 4; ++p) {
    int nn = p * 16 + r;
    ushort4 o = { f2bf(tile[c4 + 0][nn]), f2bf(tile[c4 + 1][nn]),
                  f2bf(tile[c4 + 2][nn]), f2bf(tile[c4 + 3][nn]) };
    *(ushort4*)(WT + (size_t)(n0 + nn) * K + k0 + c4) = o;
  }
}

// ---------------------------------------------------------------------------
// bf16 MFMA GEMM (validated R3-R6). A bf16 via global_load_lds.
// ---------------------------------------------------------------------------
template<bool OUT_BF16>
__global__ __launch_bounds__(256)
void gemm_mfma(const unsigned short* __restrict__ Ab,
               const unsigned short* __restrict__ Bt,
               const float* __restrict__ bias, void* __restrict__ Cv,
               int K, int lda, int ldb, int ldc) {
  __shared__ unsigned short As[128 * 64];
  __shared__ unsigned short Bs[128 * 64];
  const int tid = threadIdx.x;
  const int l = tid & 63, w = tid >> 6;
  const int m0 = blockIdx.y * 128, n0 = blockIdx.x * 128;
  const int wm = (w & 1) * 64, wn = (w >> 1) * 64;
  const int fr = l & 15, g = l >> 4;

  f32x4 acc[4][4];
#pragma unroll
  for (int i = 0; i < 4; ++i)
#pragma unroll
    for (int j = 0; j < 4; ++j) acc[i][j] = (f32x4)0.f;

  const int gr = l >> 3;
  const int gc = (l & 7) ^ gr;

  for (int kt = 0; kt < K; kt += 64) {
    __syncthreads();
#pragma unroll
    for (int q = 0; q < 4; ++q) {
      int rr = (w * 4 + q) * 8 + gr;
      GLOAD_LDS(Ab + (size_t)(m0 + rr) * lda + kt + gc * 8,
                &As[(w * 4 + q) * 512]);
      GLOAD_LDS(Bt + (size_t)(n0 + rr) * ldb + kt + gc * 8,
                &Bs[(w * 4 + q) * 512]);
    }
    __syncthreads();

#pragma unroll
    for (int s = 0; s < 2; ++s) {
      const int cofs = (((s * 4 + g) ^ (fr & 7)) << 3);
      short8 a[4], b[4];
#pragma unroll
      for (int i = 0; i < 4; ++i)
        a[i] = *(const short8*)&As[(wm + i * 16 + fr) * 64 + cofs];
#pragma unroll
      for (int j = 0; j < 4; ++j)
        b[j] = *(const short8*)&Bs[(wn + j * 16 + fr) * 64 + cofs];
#pragma unroll
      for (int i = 0; i < 4; ++i)
#pragma unroll
        for (int j = 0; j < 4; ++j)
          acc[i][j] = MFMA32(a[i], b[j], acc[i][j]);
    }
  }

#pragma unroll
  for (int j = 0; j < 4; ++j) {
    const int n = n0 + wn + j * 16 + fr;
    const float bv = bias[n];
#pragma unroll
    for (int i = 0; i < 4; ++i) {
#pragma unroll
      for (int rg = 0; rg < 4; ++rg) {
        const int m = m0 + wm + i * 16 + g * 4 + rg;
        float v = acc[i][j][rg] + bv;
        if (OUT_BF16) ((unsigned short*)Cv)[(size_t)m * ldc + n] = f2bf(v);
        else          ((float*)Cv)[(size_t)m * ldc + n] = v;
      }
    }
  }
}

// ---------------------------------------------------------------------------
// Fused per-head RMSNorm + RoPE (in-place on bf16 q,k). V handling moved to
// vtrans_kernel. Math bit-identical to the validated R0 version.
// ---------------------------------------------------------------------------
__global__ __launch_bounds__(256)
void rmsrope_kernel(unsigned short* __restrict__ qkv) {
  const int unit = blockIdx.x * 4 + (threadIdx.x >> 6);
  const int lane = threadIdx.x & 63;
  const int b = unit / (T_ * H_);
  const int rem = unit % (T_ * H_);
  const int t = rem / H_;
  const int h = rem % H_;
  const size_t base = (size_t)(b * T_ + t) * TC3;

  const int i = lane & 31;
  const float inv = __builtin_amdgcn_exp2f(-13.2877123795494f * (float)(2 * i)
                                           * (1.0f / 64.0f));
  const float ang = (float)t * inv;
  const float cs = cosf(ang);
  const float sn = sinf(ang);

  {
    const size_t idx = base + h * 64 + lane;
    float q = bf2f(qkv[idx]);
    float ss = q * q;
    ss += __shfl_xor(ss, 32); ss += __shfl_xor(ss, 16);
    ss += __shfl_xor(ss, 8);  ss += __shfl_xor(ss, 4);
    ss += __shfl_xor(ss, 2);  ss += __shfl_xor(ss, 1);
    float qn = q * (1.0f / sqrtf(ss * (1.0f / 64.0f) + 1e-6f));
    float part = __shfl_xor(qn, 32);
    float out = (lane < 32) ? (qn * cs + part * sn) : (qn * cs - part * sn);
    qkv[idx] = f2bf(out);
  }
  {
    const size_t idx = base + C_ + h * 64 + lane;
    float k = bf2f(qkv[idx]);
    float ss = k * k;
    ss += __shfl_xor(ss, 32); ss += __shfl_xor(ss, 16);
    ss += __shfl_xor(ss, 8);  ss += __shfl_xor(ss, 4);
    ss += __shfl_xor(ss, 2);  ss += __shfl_xor(ss, 1);
    float kn = k * (1.0f / sqrtf(ss * (1.0f / 64.0f) + 1e-6f));
    float part = __shfl_xor(kn, 32);
    float out = (lane < 32) ? (kn * cs + part * sn) : (kn * cs - part * sn);
    qkv[idx] = f2bf(out);
  }
}

// ---------------------------------------------------------------------------
// V transpose: bf16 v-columns of qkv -> vT (B,H,D,T) bf16, with lamb applied.
// Also writes the fp32 value output (B,H,T,D) during the load phase (moved
// here from rmsrope to save one full read of the v columns).
// Runs BEFORE flash (flash overwrites v-columns with attn output).
// ---------------------------------------------------------------------------
__global__ __launch_bounds__(256)
void vtrans_kernel(const unsigned short* __restrict__ qkv,
                   const float* __restrict__ lambp,
                   unsigned short* __restrict__ vT,
                   float* __restrict__ valOut) {
  __shared__ float tile[64][65];
  const int t0 = blockIdx.x * 64;
  const int head = blockIdx.y;             // b*H + h
  const int b = head >> 4, h = head & 15;
  const float lamb = lambp[0];
  const int r = threadIdx.x >> 4, c4 = (threadIdx.x & 15) * 4;
#pragma unroll
  for (int p = 0; p < 4; ++p) {
    int tt = p * 16 + r;
    ushort4 raw = *(const ushort4*)(
        qkv + (size_t)(b * T_ + t0 + tt) * TC3 + 2 * C_ + h * 64 + c4);
    float4 f;
    f.x = (1.f - lamb) * bf2f(raw.x) + lamb * bf2f(raw.x);
    f.y = (1.f - lamb) * bf2f(raw.y) + lamb * bf2f(raw.y);
    f.z = (1.f - lamb) * bf2f(raw.z) + lamb * bf2f(raw.z);
    f.w = (1.f - lamb) * bf2f(raw.w) + lamb * bf2f(raw.w);
    tile[tt][c4 + 0] = f.x; tile[tt][c4 + 1] = f.y;
    tile[tt][c4 + 2] = f.z; tile[tt][c4 + 3] = f.w;
    *(float4*)(valOut + ((size_t)head * T_ + t0 + tt) * D_ + c4) = f;
  }
  __syncthreads();
#pragma unroll
  for (int p = 0; p < 4; ++p) {
    int d = p * 16 + r;
    ushort4 o = { f2bf(tile[c4 + 0][d]), f2bf(tile[c4 + 1][d]),
                  f2bf(tile[c4 + 2][d]), f2bf(tile[c4 + 3][d]) };
    *(ushort4*)(vT + ((size_t)head * D_ + d) * T_ + t0 + c4) = o;
  }
}

// ---------------------------------------------------------------------------
// MFMA flash attention — v6 (in-block complementary q-tile pairing; R0 math).
// Each block owns q-tiles (qa, 15-qa): exactly 34 tile-computes per block
// (2qa+2 + 2(15-qa)+2 = 34), grid 512, uniform work, shared K/V staging
// (200 vs 272 stage-iters per (b,h)). Causal mask applied only on the 2
// diagonal K-tiles per q-tile (all earlier tiles provably unmasked).
// Softmax math (SCL mul, f2bf pack) is bit-identical to validated R0.
// ---------------------------------------------------------------------------
#define SCL_ (0.125f * 1.44269504088896f)   // 1/sqrt(D) * log2(e)

template<bool MASKED>
__device__ __forceinline__ void attn_tile(
    const unsigned short* __restrict__ Ks,
    const unsigned short* __restrict__ Vs,
    const short8 (&qf)[2][2], int qrow0 /* q0 + w*32 */, int k0,
    int fr, int quad, int f8,
    float (&l_pt)[2], f32x4 (&o)[2][4]) {
  // ---- S^T = K Q^T : C/D col = q(fr), row = key(quad*4+reg) ----
  f32x4 st[2][4];
#pragma unroll
  for (int i = 0; i < 2; ++i)
#pragma unroll
    for (int j = 0; j < 4; ++j) st[i][j] = (f32x4)0.f;

#pragma unroll
  for (int kc = 0; kc < 2; ++kc) {
    const int cofs = (((kc * 4 + quad) ^ f8) << 3);
#pragma unroll
    for (int j = 0; j < 4; ++j) {
      short8 kf = *(const short8*)&Ks[(j * 16 + fr) * 64 + cofs];
      st[0][j] = MFMA32(kf, qf[kc][0], st[0][j]);
      st[1][j] = MFMA32(kf, qf[kc][1], st[1][j]);
    }
  }

  // ---- softmax (fixed basis, per-lane) + pack P into A-frags ----
  short4b pa[2][4];
#pragma unroll
  for (int i = 0; i < 2; ++i) {
    const int qg = qrow0 + i * 16 + fr;
#pragma unroll
    for (int j = 0; j < 4; ++j) {
      const int kg = k0 + j * 16 + quad * 4;
#pragma unroll
      for (int r = 0; r < 4; ++r) {
        float arg = st[i][j][r] * SCL_;
        if (MASKED) { if (kg + r > qg) arg = -INFINITY; }
        float p = __builtin_amdgcn_exp2f(arg);
        l_pt[i] += p;
        st[i][j][r] = p;
      }
      pa[i][j] = (short4b){ (short)f2bf(st[i][j][0]), (short)f2bf(st[i][j][1]),
                            (short)f2bf(st[i][j][2]), (short)f2bf(st[i][j][3]) };
    }
  }

  // ---- O^T += P V via 16x16x16 MFMA (P in regs, V^T b64 B-frags) ----
#pragma unroll
  for (int c = 0; c < 4; ++c) {
    const int vofs = ((((c * 2 + (quad >> 1)) ^ f8) << 3) + (quad & 1) * 4);
#pragma unroll
    for (int jd = 0; jd < 4; ++jd) {
      short4b vf = *(const short4b*)&Vs[(jd * 16 + fr) * 64 + vofs];
      o[0][jd] = MFMA16(pa[0][c], vf, o[0][jd]);
      o[1][jd] = MFMA16(pa[1][c], vf, o[1][jd]);
    }
  }
}

__device__ __forceinline__ void attn_store(
    unsigned short* __restrict__ qkv, int bT, int h, int qrow0,
    int fr, int quad, float (&l_pt)[2], f32x4 (&o)[2][4]) {
#pragma unroll
  for (int i = 0; i < 2; ++i) {
    float lv = l_pt[i];
    lv += __shfl_xor(lv, 16);
    lv += __shfl_xor(lv, 32);
    float inv = 1.0f / lv;
    float invq[4];
#pragma unroll
    for (int r = 0; r < 4; ++r) invq[r] = __shfl(inv, quad * 4 + r);
#pragma unroll
    for (int jd = 0; jd < 4; ++jd) {
      const int d = jd * 16 + fr;
#pragma unroll
      for (int r = 0; r < 4; ++r) {
        const int row = qrow0 + i * 16 + quad * 4 + r;
        qkv[(size_t)(bT + row) * TC3 + 2 * C_ + h * 64 + d] =
            f2bf(o[i][jd][r] * invq[r]);
      }
    }
  }
}

__global__ __launch_bounds__(256)
void flash_mfma(unsigned short* __restrict__ qkv,
                const unsigned short* __restrict__ vT) {
  __shared__ unsigned short Qs[2][128 * 64];
  __shared__ unsigned short Ks[64 * 64];
  __shared__ unsigned short Vs[64 * 64];

  const int qa = blockIdx.x;        // 0..7
  const int qb = 15 - qa;           // 15..8  (work: 2qa+2 + 2qb+2 = 34 tiles)
  const int b  = blockIdx.z;
  const int h  = blockIdx.y;
  const int bT = b * T_;

  const int tid = threadIdx.x;
  const int w = tid >> 6, l = tid & 63;
  const int fr = l & 15, quad = l >> 4;
  const int gr = l >> 3;
  const int gc = (l & 7) ^ gr;
  const int f8 = fr & 7;

  // stage both Q tiles once
#pragma unroll
  for (int s = 0; s < 4; ++s) {
    int row = w * 32 + s * 8 + gr;
    GLOAD_LDS(qkv + (size_t)(bT + qa * 128 + row) * TC3 + h * 64 + gc * 8,
              &Qs[0][(w * 32 + s * 8) * 64]);
    GLOAD_LDS(qkv + (size_t)(bT + qb * 128 + row) * TC3 + h * 64 + gc * 8,
              &Qs[1][(w * 32 + s * 8) * 64]);
  }
  __syncthreads();

  // hoist iteration-invariant Q fragments (B-operand of S^T MFMA)
  short8 qfa[2][2], qfb[2][2];
#pragma unroll
  for (int kc = 0; kc < 2; ++kc) {
    const int cofs = (((kc * 4 + quad) ^ f8) << 3);
    qfa[kc][0] = *(const short8*)&Qs[0][(w * 32 + fr) * 64 + cofs];
    qfa[kc][1] = *(const short8*)&Qs[0][(w * 32 + 16 + fr) * 64 + cofs];
    qfb[kc][0] = *(const short8*)&Qs[1][(w * 32 + fr) * 64 + cofs];
    qfb[kc][1] = *(const short8*)&Qs[1][(w * 32 + 16 + fr) * 64 + cofs];
  }

  float la[2] = {0.f, 0.f}, lb[2] = {0.f, 0.f};
  f32x4 oa[2][4], ob[2][4];
#pragma unroll
  for (int i = 0; i < 2; ++i)
#pragma unroll
    for (int j = 0; j < 4; ++j) { oa[i][j] = (f32x4)0.f; ob[i][j] = (f32x4)0.f; }

  const int nka = 2 * qa + 2;
  const int nkb = 2 * qb + 2;
  const int qra = qa * 128 + w * 32;
  const int qrb = qb * 128 + w * 32;

  for (int kt = 0; kt < nkb; ++kt) {
    const int k0 = kt * 64;
    __syncthreads();   // prev iter's Ks/Vs reads complete (WAR)
#pragma unroll
    for (int s = 0; s < 2; ++s) {
      int row = w * 16 + s * 8;
      GLOAD_LDS(qkv + (size_t)(bT + k0 + row + gr) * TC3 + C_ + h * 64 + gc * 8,
                &Ks[row * 64]);
      GLOAD_LDS(vT + ((size_t)(b * H_ + h) * D_ + row + gr) * T_ + k0 + gc * 8,
                &Vs[row * 64]);
    }
    __syncthreads();

    if (kt < nka) {
      if (kt >= nka - 2)
        attn_tile<true >(Ks, Vs, qfa, qra, k0, fr, quad, f8, la, oa);
      else
        attn_tile<false>(Ks, Vs, qfa, qra, k0, fr, quad, f8, la, oa);
    }
    if (kt >= nkb - 2)
      attn_tile<true >(Ks, Vs, qfb, qrb, k0, fr, quad, f8, lb, ob);
    else
      attn_tile<false>(Ks, Vs, qfb, qrb, k0, fr, quad, f8, lb, ob);
  }

  // ---- epilogue: reduce l over quads, store O/l (row=q via quad*4+r) ----
  attn_store(qkv, bT, h, qra, fr, quad, la, oa);
  attn_store(qkv, bT, h, qrb, fr, quad, lb, ob);
}

// ---------------------------------------------------------------------------
// Launch. d_in: x, Wqkv, bqkv, Wproj, bproj, lamb.
// d_out: out (B*T*C f32) then value (B*H*T*D f32).
// ws: qkvb 50.3MB | WqkvT 6.3MB | WprojT 2.1MB | vT 16.8MB | xb 16.8MB.
// ---------------------------------------------------------------------------
extern "C" void kernel_launch(void* const* d_in, const int* in_sizes, int n_in,
                              void* d_out, int out_size, void* d_ws, size_t ws_size,
                              hipStream_t stream) {
  const float* x     = (const float*)d_in[0];
  const float* Wqkv  = (const float*)d_in[1];
  const float* bqkv  = (const float*)d_in[2];
  const float* Wproj = (const float*)d_in[3];
  const float* bproj = (const float*)d_in[4];
  const float* lamb  = (const float*)d_in[5];

  float* out     = (float*)d_out;
  float* val_out = out + (size_t)B_ * T_ * C_;

  unsigned short* qkvb   = (unsigned short*)d_ws;                 // B*T*3C
  unsigned short* WqkvT  = qkvb + (size_t)B_ * T_ * TC3;          // 3C x C
  unsigned short* WprojT = WqkvT + (size_t)TC3 * C_;              // C x C
  unsigned short* vT     = WprojT + (size_t)C_ * C_;              // B*H*D*T
  unsigned short* xb     = vT + (size_t)B_ * H_ * D_ * T_;        // B*T*C

  convert_bf16<<<dim3((B_ * T_ * C_) / 2048), 256, 0, stream>>>(x, xb);
  transpose_bf16<<<dim3(TC3 / 64, C_ / 64), 256, 0, stream>>>(Wqkv, WqkvT, C_, TC3);
  transpose_bf16<<<dim3(C_ / 64, C_ / 64), 256, 0, stream>>>(Wproj, WprojT, C_, C_);

  gemm_mfma<true><<<dim3(TC3 / 128, (B_ * T_) / 128), 256, 0, stream>>>(
      xb, WqkvT, bqkv, qkvb, C_, C_, C_, TC3);

  rmsrope_kernel<<<dim3((B_ * T_ * H_) / 4), 256, 0, stream>>>(qkvb);

  vtrans_kernel<<<dim3(T_ / 64, B_ * H_), 256, 0, stream>>>(qkvb, lamb, vT, val_out);

  flash_mfma<<<dim3(8, H_, B_), 256, 0, stream>>>(qkvb, vT);

  gemm_mfma<false><<<dim3(C_ / 128, (B_ * T_) / 128), 256, 0, stream>>>(
      qkvb + 2 * C_, WprojT, bproj, out, C_, TC3, C_, C_);
}

// Round 3
// 334.566 us; speedup vs baseline: 1.0198x; 1.0198x over previous
//
#include <hip/hip_runtime.h>
#include <math.h>

// Problem constants (B,T,C,H) = (4, 2048, 1024, 16), D = 64.
#define B_   4
#define T_   2048
#define C_   1024
#define H_   16
#define D_   64
#define TC3  3072   // 3*C

typedef __attribute__((ext_vector_type(8))) short short8;
typedef __attribute__((ext_vector_type(4))) short short4b;
typedef __attribute__((ext_vector_type(8))) unsigned short ushortv8;
typedef __attribute__((ext_vector_type(4))) float f32x4;

__device__ __forceinline__ float bf2f(unsigned short u) {
  unsigned int x = ((unsigned int)u) << 16;
  float f; __builtin_memcpy(&f, &x, 4); return f;
}
__device__ __forceinline__ unsigned short f2bf(float f) {   // round-nearest-even
  unsigned int x; __builtin_memcpy(&x, &f, 4);
  x += 0x7fff + ((x >> 16) & 1);
  return (unsigned short)(x >> 16);
}

#define MFMA32(a, b, c) __builtin_amdgcn_mfma_f32_16x16x32_bf16(a, b, c, 0, 0, 0)
#if __has_builtin(__builtin_amdgcn_mfma_f32_16x16x16_bf16)
#define MFMA16(a, b, c) __builtin_amdgcn_mfma_f32_16x16x16_bf16(a, b, c, 0, 0, 0)
#else
#define MFMA16(a, b, c) __builtin_amdgcn_mfma_f32_16x16x16bf16_1k(a, b, c, 0, 0, 0)
#endif

#define GLOAD_LDS(gp, lp) __builtin_amdgcn_global_load_lds( \
    (const __attribute__((address_space(1))) unsigned int*)(gp), \
    (__attribute__((address_space(3))) unsigned int*)(lp), 16, 0, 0)

// ---------------------------------------------------------------------------
// x f32 -> bf16 (lets GEMM1 use the pure-bf16 global_load_lds staging path).
// ---------------------------------------------------------------------------
__global__ __launch_bounds__(256)
void convert_bf16(const float* __restrict__ x, unsigned short* __restrict__ xb) {
  const size_t i = ((size_t)blockIdx.x * 256 + threadIdx.x) * 8;
  float4 f0 = *(const float4*)(x + i);
  float4 f1 = *(const float4*)(x + i + 4);
  ushortv8 u = { f2bf(f0.x), f2bf(f0.y), f2bf(f0.z), f2bf(f0.w),
                 f2bf(f1.x), f2bf(f1.y), f2bf(f1.z), f2bf(f1.w) };
  *(ushortv8*)(xb + i) = u;
}

// ---------------------------------------------------------------------------
// Transpose + fp32->bf16 convert: W[K][N] f32 -> WT[N][K] bf16. 64x64 tiles.
// ---------------------------------------------------------------------------
__global__ __launch_bounds__(256)
void transpose_bf16(const float* __restrict__ W, unsigned short* __restrict__ WT,
                    int K, int N) {
  __shared__ float tile[64][65];
  const int k0 = blockIdx.y * 64, n0 = blockIdx.x * 64;
  const int r = threadIdx.x >> 4, c4 = (threadIdx.x & 15) * 4;
#pragma unroll
  for (int p = 0; p < 4; ++p) {
    int kk = p * 16 + r;
    float4 v = *(const float4*)(W + (size_t)(k0 + kk) * N + n0 + c4);
    tile[kk][c4 + 0] = v.x; tile[kk][c4 + 1] = v.y;
    tile[kk][c4 + 2] = v.z; tile[kk][c4 + 3] = v.w;
  }
  __syncthreads();
#pragma unroll
  for (int p = 0; p < 4; ++p) {
    int nn = p * 16 + r;
    ushort4 o = { f2bf(tile[c4 + 0][nn]), f2bf(tile[c4 + 1][nn]),
                  f2bf(tile[c4 + 2][nn]), f2bf(tile[c4 + 3][nn]) };
    *(ushort4*)(WT + (size_t)(n0 + nn) * K + k0 + c4) = o;
  }
}

// ---------------------------------------------------------------------------
// bf16 MFMA GEMM (validated R3-R6). A bf16 via global_load_lds.
// ---------------------------------------------------------------------------
template<bool OUT_BF16>
__global__ __launch_bounds__(256)
void gemm_mfma(const unsigned short* __restrict__ Ab,
               const unsigned short* __restrict__ Bt,
               const float* __restrict__ bias, void* __restrict__ Cv,
               int K, int lda, int ldb, int ldc) {
  __shared__ unsigned short As[128 * 64];
  __shared__ unsigned short Bs[128 * 64];
  const int tid = threadIdx.x;
  const int l = tid & 63, w = tid >> 6;
  const int m0 = blockIdx.y * 128, n0 = blockIdx.x * 128;
  const int wm = (w & 1) * 64, wn = (w >> 1) * 64;
  const int fr = l & 15, g = l >> 4;

  f32x4 acc[4][4];
#pragma unroll
  for (int i = 0; i < 4; ++i)
#pragma unroll
    for (int j = 0; j < 4; ++j) acc[i][j] = (f32x4)0.f;

  const int gr = l >> 3;
  const int gc = (l & 7) ^ gr;

  for (int kt = 0; kt < K; kt += 64) {
    __syncthreads();
#pragma unroll
    for (int q = 0; q < 4; ++q) {
      int rr = (w * 4 + q) * 8 + gr;
      GLOAD_LDS(Ab + (size_t)(m0 + rr) * lda + kt + gc * 8,
                &As[(w * 4 + q) * 512]);
      GLOAD_LDS(Bt + (size_t)(n0 + rr) * ldb + kt + gc * 8,
                &Bs[(w * 4 + q) * 512]);
    }
    __syncthreads();

#pragma unroll
    for (int s = 0; s < 2; ++s) {
      const int cofs = (((s * 4 + g) ^ (fr & 7)) << 3);
      short8 a[4], b[4];
#pragma unroll
      for (int i = 0; i < 4; ++i)
        a[i] = *(const short8*)&As[(wm + i * 16 + fr) * 64 + cofs];
#pragma unroll
      for (int j = 0; j < 4; ++j)
        b[j] = *(const short8*)&Bs[(wn + j * 16 + fr) * 64 + cofs];
#pragma unroll
      for (int i = 0; i < 4; ++i)
#pragma unroll
        for (int j = 0; j < 4; ++j)
          acc[i][j] = MFMA32(a[i], b[j], acc[i][j]);
    }
  }

#pragma unroll
  for (int j = 0; j < 4; ++j) {
    const int n = n0 + wn + j * 16 + fr;
    const float bv = bias[n];
#pragma unroll
    for (int i = 0; i < 4; ++i) {
#pragma unroll
      for (int rg = 0; rg < 4; ++rg) {
        const int m = m0 + wm + i * 16 + g * 4 + rg;
        float v = acc[i][j][rg] + bv;
        if (OUT_BF16) ((unsigned short*)Cv)[(size_t)m * ldc + n] = f2bf(v);
        else          ((float*)Cv)[(size_t)m * ldc + n] = v;
      }
    }
  }
}

// ---------------------------------------------------------------------------
// Fused per-head RMSNorm + RoPE (in-place on bf16 q,k). V handling moved to
// vtrans_kernel. Math bit-identical to the validated R0 version.
// ---------------------------------------------------------------------------
__global__ __launch_bounds__(256)
void rmsrope_kernel(unsigned short* __restrict__ qkv) {
  const int unit = blockIdx.x * 4 + (threadIdx.x >> 6);
  const int lane = threadIdx.x & 63;
  const int b = unit / (T_ * H_);
  const int rem = unit % (T_ * H_);
  const int t = rem / H_;
  const int h = rem % H_;
  const size_t base = (size_t)(b * T_ + t) * TC3;

  const int i = lane & 31;
  const float inv = __builtin_amdgcn_exp2f(-13.2877123795494f * (float)(2 * i)
                                           * (1.0f / 64.0f));
  const float ang = (float)t * inv;
  const float cs = cosf(ang);
  const float sn = sinf(ang);

  {
    const size_t idx = base + h * 64 + lane;
    float q = bf2f(qkv[idx]);
    float ss = q * q;
    ss += __shfl_xor(ss, 32); ss += __shfl_xor(ss, 16);
    ss += __shfl_xor(ss, 8);  ss += __shfl_xor(ss, 4);
    ss += __shfl_xor(ss, 2);  ss += __shfl_xor(ss, 1);
    float qn = q * (1.0f / sqrtf(ss * (1.0f / 64.0f) + 1e-6f));
    float part = __shfl_xor(qn, 32);
    float out = (lane < 32) ? (qn * cs + part * sn) : (qn * cs - part * sn);
    qkv[idx] = f2bf(out);
  }
  {
    const size_t idx = base + C_ + h * 64 + lane;
    float k = bf2f(qkv[idx]);
    float ss = k * k;
    ss += __shfl_xor(ss, 32); ss += __shfl_xor(ss, 16);
    ss += __shfl_xor(ss, 8);  ss += __shfl_xor(ss, 4);
    ss += __shfl_xor(ss, 2);  ss += __shfl_xor(ss, 1);
    float kn = k * (1.0f / sqrtf(ss * (1.0f / 64.0f) + 1e-6f));
    float part = __shfl_xor(kn, 32);
    float out = (lane < 32) ? (kn * cs + part * sn) : (kn * cs - part * sn);
    qkv[idx] = f2bf(out);
  }
}

// ---------------------------------------------------------------------------
// V transpose: bf16 v-columns of qkv -> vT (B,H,D,T) bf16, with lamb applied.
// Also writes the fp32 value output (B,H,T,D) during the load phase (moved
// here from rmsrope to save one full read of the v columns).
// Runs BEFORE flash (flash overwrites v-columns with attn output).
// ---------------------------------------------------------------------------
__global__ __launch_bounds__(256)
void vtrans_kernel(const unsigned short* __restrict__ qkv,
                   const float* __restrict__ lambp,
                   unsigned short* __restrict__ vT,
                   float* __restrict__ valOut) {
  __shared__ float tile[64][65];
  const int t0 = blockIdx.x * 64;
  const int head = blockIdx.y;             // b*H + h
  const int b = head >> 4, h = head & 15;
  const float lamb = lambp[0];
  const int r = threadIdx.x >> 4, c4 = (threadIdx.x & 15) * 4;
#pragma unroll
  for (int p = 0; p < 4; ++p) {
    int tt = p * 16 + r;
    ushort4 raw = *(const ushort4*)(
        qkv + (size_t)(b * T_ + t0 + tt) * TC3 + 2 * C_ + h * 64 + c4);
    float4 f;
    f.x = (1.f - lamb) * bf2f(raw.x) + lamb * bf2f(raw.x);
    f.y = (1.f - lamb) * bf2f(raw.y) + lamb * bf2f(raw.y);
    f.z = (1.f - lamb) * bf2f(raw.z) + lamb * bf2f(raw.z);
    f.w = (1.f - lamb) * bf2f(raw.w) + lamb * bf2f(raw.w);
    tile[tt][c4 + 0] = f.x; tile[tt][c4 + 1] = f.y;
    tile[tt][c4 + 2] = f.z; tile[tt][c4 + 3] = f.w;
    *(float4*)(valOut + ((size_t)head * T_ + t0 + tt) * D_ + c4) = f;
  }
  __syncthreads();
#pragma unroll
  for (int p = 0; p < 4; ++p) {
    int d = p * 16 + r;
    ushort4 o = { f2bf(tile[c4 + 0][d]), f2bf(tile[c4 + 1][d]),
                  f2bf(tile[c4 + 2][d]), f2bf(tile[c4 + 3][d]) };
    *(ushort4*)(vT + ((size_t)head * D_ + d) * T_ + t0 + c4) = o;
  }
}

// ---------------------------------------------------------------------------
// MFMA flash attention — v7 = v4 structure (validated, 92.6us) + mask hoist.
// R2 post-mortem: the paired-q-tile variant halved blocks/CU (occupancy
// 21%->10%, VGPR 76->144) and regressed 16%. TLP > work-uniformity here.
// So: back to one q-tile per block, balanced-qt dispatch over z (each CU's
// round-robin set of 4 blocks sums to constant 68 tile-iters), grid 1024.
// Kept from R2 (refcheck-proven): attn_tile<MASKED> split — causal cmp/sel
// only on the last 2 K-tiles (proof: unmasked needs k0+63 <= q0+w*32 for
// all warps => kt < 2qt). Softmax math bit-identical to v4.
// ---------------------------------------------------------------------------
#define SCL_ (0.125f * 1.44269504088896f)   // 1/sqrt(D) * log2(e)

template<bool MASKED>
__device__ __forceinline__ void attn_tile(
    const unsigned short* __restrict__ Ks,
    const unsigned short* __restrict__ Vs,
    const short8 (&qf)[2][2], int qrow0 /* q0 + w*32 */, int k0,
    int fr, int quad, int f8,
    float (&l_pt)[2], f32x4 (&o)[2][4]) {
  // ---- S^T = K Q^T : C/D col = q(fr), row = key(quad*4+reg) ----
  f32x4 st[2][4];
#pragma unroll
  for (int i = 0; i < 2; ++i)
#pragma unroll
    for (int j = 0; j < 4; ++j) st[i][j] = (f32x4)0.f;

#pragma unroll
  for (int kc = 0; kc < 2; ++kc) {
    const int cofs = (((kc * 4 + quad) ^ f8) << 3);
#pragma unroll
    for (int j = 0; j < 4; ++j) {
      short8 kf = *(const short8*)&Ks[(j * 16 + fr) * 64 + cofs];
      st[0][j] = MFMA32(kf, qf[kc][0], st[0][j]);
      st[1][j] = MFMA32(kf, qf[kc][1], st[1][j]);
    }
  }

  // ---- softmax (fixed basis, per-lane) + pack P into A-frags ----
  short4b pa[2][4];
#pragma unroll
  for (int i = 0; i < 2; ++i) {
    const int qg = qrow0 + i * 16 + fr;
#pragma unroll
    for (int j = 0; j < 4; ++j) {
      const int kg = k0 + j * 16 + quad * 4;
#pragma unroll
      for (int r = 0; r < 4; ++r) {
        float arg = st[i][j][r] * SCL_;
        if (MASKED) { if (kg + r > qg) arg = -INFINITY; }
        float p = __builtin_amdgcn_exp2f(arg);
        l_pt[i] += p;
        st[i][j][r] = p;
      }
      pa[i][j] = (short4b){ (short)f2bf(st[i][j][0]), (short)f2bf(st[i][j][1]),
                            (short)f2bf(st[i][j][2]), (short)f2bf(st[i][j][3]) };
    }
  }

  // ---- O^T += P V via 16x16x16 MFMA (P in regs, V^T b64 B-frags) ----
#pragma unroll
  for (int c = 0; c < 4; ++c) {
    const int vofs = ((((c * 2 + (quad >> 1)) ^ f8) << 3) + (quad & 1) * 4);
#pragma unroll
    for (int jd = 0; jd < 4; ++jd) {
      short4b vf = *(const short4b*)&Vs[(jd * 16 + fr) * 64 + vofs];
      o[0][jd] = MFMA16(pa[0][c], vf, o[0][jd]);
      o[1][jd] = MFMA16(pa[1][c], vf, o[1][jd]);
    }
  }
}

__device__ __forceinline__ void attn_store(
    unsigned short* __restrict__ qkv, int bT, int h, int qrow0,
    int fr, int quad, float (&l_pt)[2], f32x4 (&o)[2][4]) {
#pragma unroll
  for (int i = 0; i < 2; ++i) {
    float lv = l_pt[i];
    lv += __shfl_xor(lv, 16);
    lv += __shfl_xor(lv, 32);
    float inv = 1.0f / lv;
    float invq[4];
#pragma unroll
    for (int r = 0; r < 4; ++r) invq[r] = __shfl(inv, quad * 4 + r);
#pragma unroll
    for (int jd = 0; jd < 4; ++jd) {
      const int d = jd * 16 + fr;
#pragma unroll
      for (int r = 0; r < 4; ++r) {
        const int row = qrow0 + i * 16 + quad * 4 + r;
        qkv[(size_t)(bT + row) * TC3 + 2 * C_ + h * 64 + d] =
            f2bf(o[i][jd][r] * invq[r]);
      }
    }
  }
}

__global__ __launch_bounds__(256)
void flash_mfma(unsigned short* __restrict__ qkv,
                const unsigned short* __restrict__ vT) {
  __shared__ unsigned short Qs[128 * 64];
  __shared__ unsigned short Ks[64 * 64];
  __shared__ unsigned short Vs[64 * 64];

  // balanced work mapping: qts {x, 15-x, (x+8)&15, 15-((x+8)&15)} per CU
  const int z = blockIdx.z;
  const int xx = ((int)blockIdx.x + ((z >> 1) << 3)) & 15;
  const int qt = (z & 1) ? (15 - xx) : xx;
  const int b  = z;
  const int h  = blockIdx.y;
  const int bT = b * T_;

  const int tid = threadIdx.x;
  const int w = tid >> 6, l = tid & 63;
  const int fr = l & 15, quad = l >> 4;
  const int q0 = qt * 128;
  const int gr = l >> 3;
  const int gc = (l & 7) ^ gr;
  const int f8 = fr & 7;

  // stage Q once
#pragma unroll
  for (int s = 0; s < 4; ++s) {
    int row = w * 32 + s * 8 + gr;
    GLOAD_LDS(qkv + (size_t)(bT + q0 + row) * TC3 + h * 64 + gc * 8,
              &Qs[(w * 32 + s * 8) * 64]);
  }
  __syncthreads();

  // hoist iteration-invariant Q fragments (B-operand of S^T MFMA)
  short8 qf[2][2];
#pragma unroll
  for (int kc = 0; kc < 2; ++kc) {
    const int cofs = (((kc * 4 + quad) ^ f8) << 3);
    qf[kc][0] = *(const short8*)&Qs[(w * 32 + fr) * 64 + cofs];
    qf[kc][1] = *(const short8*)&Qs[(w * 32 + 16 + fr) * 64 + cofs];
  }

  float l_pt[2] = {0.f, 0.f};
  f32x4 o[2][4];
#pragma unroll
  for (int i = 0; i < 2; ++i)
#pragma unroll
    for (int j = 0; j < 4; ++j) o[i][j] = (f32x4)0.f;

  const int nk = 2 * qt + 2;
  const int qr0 = q0 + w * 32;

  for (int kt = 0; kt < nk; ++kt) {
    const int k0 = kt * 64;
    __syncthreads();   // prev iter's Ks/Vs reads complete (WAR)
#pragma unroll
    for (int s = 0; s < 2; ++s) {
      int row = w * 16 + s * 8;
      GLOAD_LDS(qkv + (size_t)(bT + k0 + row + gr) * TC3 + C_ + h * 64 + gc * 8,
                &Ks[row * 64]);
      GLOAD_LDS(vT + ((size_t)(b * H_ + h) * D_ + row + gr) * T_ + k0 + gc * 8,
                &Vs[row * 64]);
    }
    __syncthreads();

    if (kt < nk - 2)
      attn_tile<false>(Ks, Vs, qf, qr0, k0, fr, quad, f8, l_pt, o);
    else
      attn_tile<true >(Ks, Vs, qf, qr0, k0, fr, quad, f8, l_pt, o);
  }

  // ---- epilogue: reduce l over quads, store O/l (row=q via quad*4+r) ----
  attn_store(qkv, bT, h, qr0, fr, quad, l_pt, o);
}

// ---------------------------------------------------------------------------
// Launch. d_in: x, Wqkv, bqkv, Wproj, bproj, lamb.
// d_out: out (B*T*C f32) then value (B*H*T*D f32).
// ws: qkvb 50.3MB | WqkvT 6.3MB | WprojT 2.1MB | vT 16.8MB | xb 16.8MB.
// ---------------------------------------------------------------------------
extern "C" void kernel_launch(void* const* d_in, const int* in_sizes, int n_in,
                              void* d_out, int out_size, void* d_ws, size_t ws_size,
                              hipStream_t stream) {
  const float* x     = (const float*)d_in[0];
  const float* Wqkv  = (const float*)d_in[1];
  const float* bqkv  = (const float*)d_in[2];
  const float* Wproj = (const float*)d_in[3];
  const float* bproj = (const float*)d_in[4];
  const float* lamb  = (const float*)d_in[5];

  float* out     = (float*)d_out;
  float* val_out = out + (size_t)B_ * T_ * C_;

  unsigned short* qkvb   = (unsigned short*)d_ws;                 // B*T*3C
  unsigned short* WqkvT  = qkvb + (size_t)B_ * T_ * TC3;          // 3C x C
  unsigned short* WprojT = WqkvT + (size_t)TC3 * C_;              // C x C
  unsigned short* vT     = WprojT + (size_t)C_ * C_;              // B*H*D*T
  unsigned short* xb     = vT + (size_t)B_ * H_ * D_ * T_;        // B*T*C

  convert_bf16<<<dim3((B_ * T_ * C_) / 2048), 256, 0, stream>>>(x, xb);
  transpose_bf16<<<dim3(TC3 / 64, C_ / 64), 256, 0, stream>>>(Wqkv, WqkvT, C_, TC3);
  transpose_bf16<<<dim3(C_ / 64, C_ / 64), 256, 0, stream>>>(Wproj, WprojT, C_, C_);

  gemm_mfma<true><<<dim3(TC3 / 128, (B_ * T_) / 128), 256, 0, stream>>>(
      xb, WqkvT, bqkv, qkvb, C_, C_, C_, TC3);

  rmsrope_kernel<<<dim3((B_ * T_ * H_) / 4), 256, 0, stream>>>(qkvb);

  vtrans_kernel<<<dim3(T_ / 64, B_ * H_), 256, 0, stream>>>(qkvb, lamb, vT, val_out);

  flash_mfma<<<dim3(16, H_, B_), 256, 0, stream>>>(qkvb, vT);

  gemm_mfma<false><<<dim3(C_ / 128, (B_ * T_) / 128), 256, 0, stream>>>(
      qkvb + 2 * C_, WprojT, bproj, out, C_, TC3, C_, C_);
}

// Round 4
// 318.452 us; speedup vs baseline: 1.0714x; 1.0506x over previous
//
#include <hip/hip_runtime.h>
#include <math.h>

// Problem constants (B,T,C,H) = (4, 2048, 1024, 16), D = 64.
#define B_   4
#define T_   2048
#define C_   1024
#define H_   16
#define D_   64
#define TC3  3072   // 3*C

typedef __attribute__((ext_vector_type(8))) short short8;
typedef __attribute__((ext_vector_type(4))) short short4b;
typedef __attribute__((ext_vector_type(8))) unsigned short ushortv8;
typedef __attribute__((ext_vector_type(4))) float f32x4;
typedef __attribute__((ext_vector_type(4))) __bf16 bf16x4;

__device__ __forceinline__ float bf2f(unsigned short u) {
  unsigned int x = ((unsigned int)u) << 16;
  float f; __builtin_memcpy(&f, &x, 4); return f;
}
__device__ __forceinline__ unsigned short f2bf(float f) {   // round-nearest-even
  unsigned int x; __builtin_memcpy(&x, &f, 4);
  x += 0x7fff + ((x >> 16) & 1);
  return (unsigned short)(x >> 16);
}

#define MFMA32(a, b, c) __builtin_amdgcn_mfma_f32_16x16x32_bf16(a, b, c, 0, 0, 0)
#if __has_builtin(__builtin_amdgcn_mfma_f32_16x16x16_bf16)
#define MFMA16(a, b, c) __builtin_amdgcn_mfma_f32_16x16x16_bf16(a, b, c, 0, 0, 0)
#else
#define MFMA16(a, b, c) __builtin_amdgcn_mfma_f32_16x16x16bf16_1k(a, b, c, 0, 0, 0)
#endif

#define GLOAD_LDS(gp, lp) __builtin_amdgcn_global_load_lds( \
    (const __attribute__((address_space(1))) unsigned int*)(gp), \
    (__attribute__((address_space(3))) unsigned int*)(lp), 16, 0, 0)

// ---------------------------------------------------------------------------
// x f32 -> bf16 (lets GEMM1 use the pure-bf16 global_load_lds staging path).
// ---------------------------------------------------------------------------
__global__ __launch_bounds__(256)
void convert_bf16(const float* __restrict__ x, unsigned short* __restrict__ xb) {
  const size_t i = ((size_t)blockIdx.x * 256 + threadIdx.x) * 8;
  float4 f0 = *(const float4*)(x + i);
  float4 f1 = *(const float4*)(x + i + 4);
  ushortv8 u = { f2bf(f0.x), f2bf(f0.y), f2bf(f0.z), f2bf(f0.w),
                 f2bf(f1.x), f2bf(f1.y), f2bf(f1.z), f2bf(f1.w) };
  *(ushortv8*)(xb + i) = u;
}

// ---------------------------------------------------------------------------
// Transpose + fp32->bf16 convert: W[K][N] f32 -> WT[N][K] bf16. 64x64 tiles.
// ---------------------------------------------------------------------------
__global__ __launch_bounds__(256)
void transpose_bf16(const float* __restrict__ W, unsigned short* __restrict__ WT,
                    int K, int N) {
  __shared__ float tile[64][65];
  const int k0 = blockIdx.y * 64, n0 = blockIdx.x * 64;
  const int r = threadIdx.x >> 4, c4 = (threadIdx.x & 15) * 4;
#pragma unroll
  for (int p = 0; p < 4; ++p) {
    int kk = p * 16 + r;
    float4 v = *(const float4*)(W + (size_t)(k0 + kk) * N + n0 + c4);
    tile[kk][c4 + 0] = v.x; tile[kk][c4 + 1] = v.y;
    tile[kk][c4 + 2] = v.z; tile[kk][c4 + 3] = v.w;
  }
  __syncthreads();
#pragma unroll
  for (int p = 0; p < 4; ++p) {
    int nn = p * 16 + r;
    ushort4 o = { f2bf(tile[c4 + 0][nn]), f2bf(tile[c4 + 1][nn]),
                  f2bf(tile[c4 + 2][nn]), f2bf(tile[c4 + 3][nn]) };
    *(ushort4*)(WT + (size_t)(n0 + nn) * K + k0 + c4) = o;
  }
}

// ---------------------------------------------------------------------------
// bf16 MFMA GEMM (validated R3-R6). A bf16 via global_load_lds.
// ---------------------------------------------------------------------------
template<bool OUT_BF16>
__global__ __launch_bounds__(256)
void gemm_mfma(const unsigned short* __restrict__ Ab,
               const unsigned short* __restrict__ Bt,
               const float* __restrict__ bias, void* __restrict__ Cv,
               int K, int lda, int ldb, int ldc) {
  __shared__ unsigned short As[128 * 64];
  __shared__ unsigned short Bs[128 * 64];
  const int tid = threadIdx.x;
  const int l = tid & 63, w = tid >> 6;
  const int m0 = blockIdx.y * 128, n0 = blockIdx.x * 128;
  const int wm = (w & 1) * 64, wn = (w >> 1) * 64;
  const int fr = l & 15, g = l >> 4;

  f32x4 acc[4][4];
#pragma unroll
  for (int i = 0; i < 4; ++i)
#pragma unroll
    for (int j = 0; j < 4; ++j) acc[i][j] = (f32x4)0.f;

  const int gr = l >> 3;
  const int gc = (l & 7) ^ gr;

  for (int kt = 0; kt < K; kt += 64) {
    __syncthreads();
#pragma unroll
    for (int q = 0; q < 4; ++q) {
      int rr = (w * 4 + q) * 8 + gr;
      GLOAD_LDS(Ab + (size_t)(m0 + rr) * lda + kt + gc * 8,
                &As[(w * 4 + q) * 512]);
      GLOAD_LDS(Bt + (size_t)(n0 + rr) * ldb + kt + gc * 8,
                &Bs[(w * 4 + q) * 512]);
    }
    __syncthreads();

#pragma unroll
    for (int s = 0; s < 2; ++s) {
      const int cofs = (((s * 4 + g) ^ (fr & 7)) << 3);
      short8 a[4], b[4];
#pragma unroll
      for (int i = 0; i < 4; ++i)
        a[i] = *(const short8*)&As[(wm + i * 16 + fr) * 64 + cofs];
#pragma unroll
      for (int j = 0; j < 4; ++j)
        b[j] = *(const short8*)&Bs[(wn + j * 16 + fr) * 64 + cofs];
#pragma unroll
      for (int i = 0; i < 4; ++i)
#pragma unroll
        for (int j = 0; j < 4; ++j)
          acc[i][j] = MFMA32(a[i], b[j], acc[i][j]);
    }
  }

#pragma unroll
  for (int j = 0; j < 4; ++j) {
    const int n = n0 + wn + j * 16 + fr;
    const float bv = bias[n];
#pragma unroll
    for (int i = 0; i < 4; ++i) {
#pragma unroll
      for (int rg = 0; rg < 4; ++rg) {
        const int m = m0 + wm + i * 16 + g * 4 + rg;
        float v = acc[i][j][rg] + bv;
        if (OUT_BF16) ((unsigned short*)Cv)[(size_t)m * ldc + n] = f2bf(v);
        else          ((float*)Cv)[(size_t)m * ldc + n] = v;
      }
    }
  }
}

// ---------------------------------------------------------------------------
// Fused per-head RMSNorm + RoPE (in-place on bf16 q,k). V handling moved to
// vtrans_kernel. Math bit-identical to the validated R0 version.
// ---------------------------------------------------------------------------
__global__ __launch_bounds__(256)
void rmsrope_kernel(unsigned short* __restrict__ qkv) {
  const int unit = blockIdx.x * 4 + (threadIdx.x >> 6);
  const int lane = threadIdx.x & 63;
  const int b = unit / (T_ * H_);
  const int rem = unit % (T_ * H_);
  const int t = rem / H_;
  const int h = rem % H_;
  const size_t base = (size_t)(b * T_ + t) * TC3;

  const int i = lane & 31;
  const float inv = __builtin_amdgcn_exp2f(-13.2877123795494f * (float)(2 * i)
                                           * (1.0f / 64.0f));
  const float ang = (float)t * inv;
  const float cs = cosf(ang);
  const float sn = sinf(ang);

  {
    const size_t idx = base + h * 64 + lane;
    float q = bf2f(qkv[idx]);
    float ss = q * q;
    ss += __shfl_xor(ss, 32); ss += __shfl_xor(ss, 16);
    ss += __shfl_xor(ss, 8);  ss += __shfl_xor(ss, 4);
    ss += __shfl_xor(ss, 2);  ss += __shfl_xor(ss, 1);
    float qn = q * (1.0f / sqrtf(ss * (1.0f / 64.0f) + 1e-6f));
    float part = __shfl_xor(qn, 32);
    float out = (lane < 32) ? (qn * cs + part * sn) : (qn * cs - part * sn);
    qkv[idx] = f2bf(out);
  }
  {
    const size_t idx = base + C_ + h * 64 + lane;
    float k = bf2f(qkv[idx]);
    float ss = k * k;
    ss += __shfl_xor(ss, 32); ss += __shfl_xor(ss, 16);
    ss += __shfl_xor(ss, 8);  ss += __shfl_xor(ss, 4);
    ss += __shfl_xor(ss, 2);  ss += __shfl_xor(ss, 1);
    float kn = k * (1.0f / sqrtf(ss * (1.0f / 64.0f) + 1e-6f));
    float part = __shfl_xor(kn, 32);
    float out = (lane < 32) ? (kn * cs + part * sn) : (kn * cs - part * sn);
    qkv[idx] = f2bf(out);
  }
}

// ---------------------------------------------------------------------------
// V transpose: bf16 v-columns of qkv -> vT (B,H,D,T) bf16, with lamb applied.
// Also writes the fp32 value output (B,H,T,D) during the load phase (moved
// here from rmsrope to save one full read of the v columns).
// Runs BEFORE flash (flash overwrites v-columns with attn output).
// ---------------------------------------------------------------------------
__global__ __launch_bounds__(256)
void vtrans_kernel(const unsigned short* __restrict__ qkv,
                   const float* __restrict__ lambp,
                   unsigned short* __restrict__ vT,
                   float* __restrict__ valOut) {
  __shared__ float tile[64][65];
  const int t0 = blockIdx.x * 64;
  const int head = blockIdx.y;             // b*H + h
  const int b = head >> 4, h = head & 15;
  const float lamb = lambp[0];
  const int r = threadIdx.x >> 4, c4 = (threadIdx.x & 15) * 4;
#pragma unroll
  for (int p = 0; p < 4; ++p) {
    int tt = p * 16 + r;
    ushort4 raw = *(const ushort4*)(
        qkv + (size_t)(b * T_ + t0 + tt) * TC3 + 2 * C_ + h * 64 + c4);
    float4 f;
    f.x = (1.f - lamb) * bf2f(raw.x) + lamb * bf2f(raw.x);
    f.y = (1.f - lamb) * bf2f(raw.y) + lamb * bf2f(raw.y);
    f.z = (1.f - lamb) * bf2f(raw.z) + lamb * bf2f(raw.z);
    f.w = (1.f - lamb) * bf2f(raw.w) + lamb * bf2f(raw.w);
    tile[tt][c4 + 0] = f.x; tile[tt][c4 + 1] = f.y;
    tile[tt][c4 + 2] = f.z; tile[tt][c4 + 3] = f.w;
    *(float4*)(valOut + ((size_t)head * T_ + t0 + tt) * D_ + c4) = f;
  }
  __syncthreads();
#pragma unroll
  for (int p = 0; p < 4; ++p) {
    int d = p * 16 + r;
    ushort4 o = { f2bf(tile[c4 + 0][d]), f2bf(tile[c4 + 1][d]),
                  f2bf(tile[c4 + 2][d]), f2bf(tile[c4 + 3][d]) };
    *(ushort4*)(vT + ((size_t)head * D_ + d) * T_ + t0 + c4) = o;
  }
}

// ---------------------------------------------------------------------------
// MFMA flash attention — v8 = exact v4/R0 structure (validated 92.6us, 76
// VGPR, one always-masked tile body — R2/R3 showed ANY VGPR growth kills
// occupancy and loses more than the saved VALU ops) with two zero-register
// VALU cuts:
//  * P pack: scalar (__bf16) casts — compiler emits v_cvt_pk_bf16_f32
//    (2 elem/inst) vs hand RNE bit-manip (~4 inst/elem). ~96 fewer VALU
//    insts per tile, RNE-identical for P in [0,1].
//  * s_setprio(1) around the two MFMA clusters (T5: proven +4-7% on attn).
// ---------------------------------------------------------------------------
#define SCL_ (0.125f * 1.44269504088896f)   // 1/sqrt(D) * log2(e)

__device__ __forceinline__ void attn_tile(
    const unsigned short* __restrict__ Ks,
    const unsigned short* __restrict__ Vs,
    const short8 (&qf)[2][2], int qrow0 /* q0 + w*32 */, int k0,
    int fr, int quad, int f8,
    float (&l_pt)[2], f32x4 (&o)[2][4]) {
  // ---- S^T = K Q^T : C/D col = q(fr), row = key(quad*4+reg) ----
  f32x4 st[2][4];
#pragma unroll
  for (int i = 0; i < 2; ++i)
#pragma unroll
    for (int j = 0; j < 4; ++j) st[i][j] = (f32x4)0.f;

  __builtin_amdgcn_s_setprio(1);
#pragma unroll
  for (int kc = 0; kc < 2; ++kc) {
    const int cofs = (((kc * 4 + quad) ^ f8) << 3);
#pragma unroll
    for (int j = 0; j < 4; ++j) {
      short8 kf = *(const short8*)&Ks[(j * 16 + fr) * 64 + cofs];
      st[0][j] = MFMA32(kf, qf[kc][0], st[0][j]);
      st[1][j] = MFMA32(kf, qf[kc][1], st[1][j]);
    }
  }
  __builtin_amdgcn_s_setprio(0);

  // ---- softmax (fixed basis, per-lane) + pack P into A-frags ----
  short4b pa[2][4];
#pragma unroll
  for (int i = 0; i < 2; ++i) {
    const int qg = qrow0 + i * 16 + fr;
#pragma unroll
    for (int j = 0; j < 4; ++j) {
      const int kg = k0 + j * 16 + quad * 4;
#pragma unroll
      for (int r = 0; r < 4; ++r) {
        float arg = st[i][j][r] * SCL_;
        if (kg + r > qg) arg = -INFINITY;   // branchless causal mask
        float p = __builtin_amdgcn_exp2f(arg);
        l_pt[i] += p;
        st[i][j][r] = p;
      }
      bf16x4 pb = { (__bf16)st[i][j][0], (__bf16)st[i][j][1],
                    (__bf16)st[i][j][2], (__bf16)st[i][j][3] };
      pa[i][j] = __builtin_bit_cast(short4b, pb);
    }
  }

  // ---- O^T += P V via 16x16x16 MFMA (P in regs, V^T b64 B-frags) ----
  __builtin_amdgcn_s_setprio(1);
#pragma unroll
  for (int c = 0; c < 4; ++c) {
    const int vofs = ((((c * 2 + (quad >> 1)) ^ f8) << 3) + (quad & 1) * 4);
#pragma unroll
    for (int jd = 0; jd < 4; ++jd) {
      short4b vf = *(const short4b*)&Vs[(jd * 16 + fr) * 64 + vofs];
      o[0][jd] = MFMA16(pa[0][c], vf, o[0][jd]);
      o[1][jd] = MFMA16(pa[1][c], vf, o[1][jd]);
    }
  }
  __builtin_amdgcn_s_setprio(0);
}

__device__ __forceinline__ void attn_store(
    unsigned short* __restrict__ qkv, int bT, int h, int qrow0,
    int fr, int quad, float (&l_pt)[2], f32x4 (&o)[2][4]) {
#pragma unroll
  for (int i = 0; i < 2; ++i) {
    float lv = l_pt[i];
    lv += __shfl_xor(lv, 16);
    lv += __shfl_xor(lv, 32);
    float inv = 1.0f / lv;
    float invq[4];
#pragma unroll
    for (int r = 0; r < 4; ++r) invq[r] = __shfl(inv, quad * 4 + r);
#pragma unroll
    for (int jd = 0; jd < 4; ++jd) {
      const int d = jd * 16 + fr;
#pragma unroll
      for (int r = 0; r < 4; ++r) {
        const int row = qrow0 + i * 16 + quad * 4 + r;
        qkv[(size_t)(bT + row) * TC3 + 2 * C_ + h * 64 + d] =
            f2bf(o[i][jd][r] * invq[r]);
      }
    }
  }
}

__global__ __launch_bounds__(256)
void flash_mfma(unsigned short* __restrict__ qkv,
                const unsigned short* __restrict__ vT) {
  __shared__ unsigned short Qs[128 * 64];
  __shared__ unsigned short Ks[64 * 64];
  __shared__ unsigned short Vs[64 * 64];

  // balanced work mapping: qts {x, 15-x, (x+8)&15, 15-((x+8)&15)} per CU
  const int z = blockIdx.z;
  const int xx = ((int)blockIdx.x + ((z >> 1) << 3)) & 15;
  const int qt = (z & 1) ? (15 - xx) : xx;
  const int b  = z;
  const int h  = blockIdx.y;
  const int bT = b * T_;

  const int tid = threadIdx.x;
  const int w = tid >> 6, l = tid & 63;
  const int fr = l & 15, quad = l >> 4;
  const int q0 = qt * 128;
  const int gr = l >> 3;
  const int gc = (l & 7) ^ gr;
  const int f8 = fr & 7;

  // stage Q once
#pragma unroll
  for (int s = 0; s < 4; ++s) {
    int row = w * 32 + s * 8 + gr;
    GLOAD_LDS(qkv + (size_t)(bT + q0 + row) * TC3 + h * 64 + gc * 8,
              &Qs[(w * 32 + s * 8) * 64]);
  }
  __syncthreads();

  // hoist iteration-invariant Q fragments (B-operand of S^T MFMA)
  short8 qf[2][2];
#pragma unroll
  for (int kc = 0; kc < 2; ++kc) {
    const int cofs = (((kc * 4 + quad) ^ f8) << 3);
    qf[kc][0] = *(const short8*)&Qs[(w * 32 + fr) * 64 + cofs];
    qf[kc][1] = *(const short8*)&Qs[(w * 32 + 16 + fr) * 64 + cofs];
  }

  float l_pt[2] = {0.f, 0.f};
  f32x4 o[2][4];
#pragma unroll
  for (int i = 0; i < 2; ++i)
#pragma unroll
    for (int j = 0; j < 4; ++j) o[i][j] = (f32x4)0.f;

  const int nk = 2 * qt + 2;
  const int qr0 = q0 + w * 32;

  for (int kt = 0; kt < nk; ++kt) {
    const int k0 = kt * 64;
    __syncthreads();   // prev iter's Ks/Vs reads complete (WAR)
#pragma unroll
    for (int s = 0; s < 2; ++s) {
      int row = w * 16 + s * 8;
      GLOAD_LDS(qkv + (size_t)(bT + k0 + row + gr) * TC3 + C_ + h * 64 + gc * 8,
                &Ks[row * 64]);
      GLOAD_LDS(vT + ((size_t)(b * H_ + h) * D_ + row + gr) * T_ + k0 + gc * 8,
                &Vs[row * 64]);
    }
    __syncthreads();

    attn_tile(Ks, Vs, qf, qr0, k0, fr, quad, f8, l_pt, o);
  }

  // ---- epilogue: reduce l over quads, store O/l (row=q via quad*4+r) ----
  attn_store(qkv, bT, h, qr0, fr, quad, l_pt, o);
}

// ---------------------------------------------------------------------------
// Launch. d_in: x, Wqkv, bqkv, Wproj, bproj, lamb.
// d_out: out (B*T*C f32) then value (B*H*T*D f32).
// ws: qkvb 50.3MB | WqkvT 6.3MB | WprojT 2.1MB | vT 16.8MB | xb 16.8MB.
// ---------------------------------------------------------------------------
extern "C" void kernel_launch(void* const* d_in, const int* in_sizes, int n_in,
                              void* d_out, int out_size, void* d_ws, size_t ws_size,
                              hipStream_t stream) {
  const float* x     = (const float*)d_in[0];
  const float* Wqkv  = (const float*)d_in[1];
  const float* bqkv  = (const float*)d_in[2];
  const float* Wproj = (const float*)d_in[3];
  const float* bproj = (const float*)d_in[4];
  const float* lamb  = (const float*)d_in[5];

  float* out     = (float*)d_out;
  float* val_out = out + (size_t)B_ * T_ * C_;

  unsigned short* qkvb   = (unsigned short*)d_ws;                 // B*T*3C
  unsigned short* WqkvT  = qkvb + (size_t)B_ * T_ * TC3;          // 3C x C
  unsigned short* WprojT = WqkvT + (size_t)TC3 * C_;              // C x C
  unsigned short* vT     = WprojT + (size_t)C_ * C_;              // B*H*D*T
  unsigned short* xb     = vT + (size_t)B_ * H_ * D_ * T_;        // B*T*C

  convert_bf16<<<dim3((B_ * T_ * C_) / 2048), 256, 0, stream>>>(x, xb);
  transpose_bf16<<<dim3(TC3 / 64, C_ / 64), 256, 0, stream>>>(Wqkv, WqkvT, C_, TC3);
  transpose_bf16<<<dim3(C_ / 64, C_ / 64), 256, 0, stream>>>(Wproj, WprojT, C_, C_);

  gemm_mfma<true><<<dim3(TC3 / 128, (B_ * T_) / 128), 256, 0, stream>>>(
      xb, WqkvT, bqkv, qkvb, C_, C_, C_, TC3);

  rmsrope_kernel<<<dim3((B_ * T_ * H_) / 4), 256, 0, stream>>>(qkvb);

  vtrans_kernel<<<dim3(T_ / 64, B_ * H_), 256, 0, stream>>>(qkvb, lamb, vT, val_out);

  flash_mfma<<<dim3(16, H_, B_), 256, 0, stream>>>(qkvb, vT);

  gemm_mfma<false><<<dim3(C_ / 128, (B_ * T_) / 128), 256, 0, stream>>>(
      qkvb + 2 * C_, WprojT, bproj, out, C_, TC3, C_, C_);
}